// Round 3
// baseline (335.177 us; speedup 1.0000x reference)
//
#include <hip/hip_runtime.h>
#include <math.h>

#define NCH 16    // C
#define KNB 10    // K neighbors
#define NTOP 4    // TOPK

// Kernel 1: transpose x (B,C,E) -> xT (B,E,C) so each edge's 16 channels are
// one contiguous, aligned 64-byte line (single cache line per gather).
__global__ __launch_bounds__(256) void transpose_kernel(
    const float* __restrict__ x, float* __restrict__ xT, int E)
{
    const int b = blockIdx.y;
    const int e = blockIdx.x * blockDim.x + threadIdx.x;
    if (e >= E) return;
    const float* xb = x + (size_t)b * NCH * E;
    float v[NCH];
#pragma unroll
    for (int c = 0; c < NCH; ++c) v[c] = xb[(size_t)c * E + e];   // coalesced per c
    float4* dst = (float4*)(xT + ((size_t)b * E + e) * NCH);      // coalesced 64B/thread
    dst[0] = make_float4(v[0],  v[1],  v[2],  v[3]);
    dst[1] = make_float4(v[4],  v[5],  v[6],  v[7]);
    dst[2] = make_float4(v[8],  v[9],  v[10], v[11]);
    dst[3] = make_float4(v[12], v[13], v[14], v[15]);
}

// Selection must BIT-MATCH the numpy f32 reference chain:
//   eG = np.einsum('bcek,c->bek') : sequential f32 accumulation over c, no FMA
//   l  = fl32(fl32(eG + eX) + cb) : left-associative adds
//   t  = fl32(exp(-l))            : correctly-rounded f32 exp (via f64 exp)
//   sim= 1.0f / (1.0f + t)        : IEEE f32, bit-reproducible
// Top-4 on these f32 sims, lowest-index-first on exact ties (stable top_k).
__global__ __launch_bounds__(256) void atten_kernel(
    const float* __restrict__ xT,      // (B,E,C)
    const int*   __restrict__ Gi,      // (B,E,K)
    const float* __restrict__ conv_w,  // (32,)
    const float* __restrict__ conv_b,  // (1,)
    const float* __restrict__ rconv_w, // (32,)
    const float* __restrict__ rconv_b, // (1,)
    float*       __restrict__ out,     // (B,C,E)
    int E)
{
    const int b = blockIdx.y;
    const int e = blockIdx.x * blockDim.x + threadIdx.x;
    if (e >= E) return;

    // Weights: wave-uniform addresses -> scalar loads.
    float wcx[NCH], wcg[NCH], wrx[NCH], wrg[NCH];
#pragma unroll
    for (int c = 0; c < NCH; ++c) {
        wcx[c] = conv_w[c];
        wcg[c] = conv_w[NCH + c];
        wrx[c] = rconv_w[c];
        wrg[c] = rconv_w[NCH + c];
    }
    const float  cb32 = conv_b[0];
    const double rb   = (double)rconv_b[0];

    // Own feature row (64B aligned contiguous).
    const float4* xrow = (const float4*)(xT + ((size_t)b * E + e) * NCH);
    float xe[NCH];
#pragma unroll
    for (int i = 0; i < 4; ++i) {
        float4 t = xrow[i];
        xe[4*i+0] = t.x; xe[4*i+1] = t.y; xe[4*i+2] = t.z; xe[4*i+3] = t.w;
    }

    // eX for the sim logit: np-exact f32 sequential sum over c, NO FMA.
    float sX_c;
    {
#pragma clang fp contract(off)
        float s = 0.0f;
#pragma unroll
        for (int c = 0; c < NCH; ++c) s = s + xe[c] * wcx[c];
        sX_c = s;
    }
    // Base dot for rw (accuracy only; comparison is bf16-rounded -> forgiving).
    double xs_r = rb;
#pragma unroll
    for (int c = 0; c < NCH; ++c) xs_r += (double)xe[c] * (double)wrx[c];

    // Neighbor indices (kept in registers).
    const int* gi = Gi + ((size_t)b * E + e) * KNB;
    int j[KNB];
#pragma unroll
    for (int k = 0; k < KNB; ++k) j[k] = gi[k];

    // Pass 1: f32 sims exactly as numpy computes them.
    float sim[KNB];
#pragma unroll
    for (int k = 0; k < KNB; ++k) {
        const float4* grow = (const float4*)(xT + ((size_t)b * E + j[k]) * NCH);
        float g[NCH];
#pragma unroll
        for (int i = 0; i < 4; ++i) {
            float4 gv = grow[i];
            g[4*i+0] = gv.x; g[4*i+1] = gv.y; g[4*i+2] = gv.z; g[4*i+3] = gv.w;
        }
        float sv;
        {
#pragma clang fp contract(off)
            float s = 0.0f;
#pragma unroll
            for (int c = 0; c < NCH; ++c) s = s + g[c] * wcg[c];   // seq c-order, no FMA
            float l = (s + sX_c) + cb32;                           // left-assoc adds
            float t = (float)exp(-(double)l);                      // correctly-rounded f32 exp
            sv = 1.0f / (1.0f + t);                                // IEEE f32
        }
        sim[k] = sv;
    }

    // Pass 2: top-4 (strict > keeps LOWEST index on exact f32 ties, matching
    // stable lax.top_k / stable argsort), re-gather winner, accumulate.
    float acc[NCH];
#pragma unroll
    for (int c = 0; c < NCH; ++c) acc[c] = 0.f;

    unsigned used = 0;
#pragma unroll
    for (int t = 0; t < NTOP; ++t) {
        float best = -INFINITY; int bi = 0; int bj = 0;
#pragma unroll
        for (int k = 0; k < KNB; ++k) {
            const bool ok = !(used & (1u << k)) && (sim[k] > best);
            best = ok ? sim[k] : best;
            bi   = ok ? k      : bi;
            bj   = ok ? j[k]   : bj;
        }
        used |= 1u << bi;

        const float4* grow = (const float4*)(xT + ((size_t)b * E + bj) * NCH);
        float g[NCH];
#pragma unroll
        for (int i = 0; i < 4; ++i) {
            float4 gv = grow[i];
            g[4*i+0] = gv.x; g[4*i+1] = gv.y; g[4*i+2] = gv.z; g[4*i+3] = gv.w;
        }
        double r = xs_r;
#pragma unroll
        for (int c = 0; c < NCH; ++c) r += (double)g[c] * (double)wrg[c];
        const float rw = (float)(1.0 / (1.0 + exp(-r)));   // accurate sigmoid
#pragma unroll
        for (int c = 0; c < NCH; ++c) acc[c] += g[c] * rw;
    }

    // out (B,C,E): 16 coalesced store passes.
    float* ob = out + (size_t)b * NCH * E;
#pragma unroll
    for (int c = 0; c < NCH; ++c) ob[(size_t)c * E + e] = xe[c] + acc[c];
}

extern "C" void kernel_launch(void* const* d_in, const int* in_sizes, int n_in,
                              void* d_out, int out_size, void* d_ws, size_t ws_size,
                              hipStream_t stream) {
    const float* x       = (const float*)d_in[0];  // (B,C,E,1) fp32
    const int*   Gi      = (const int*)  d_in[1];  // (B,E,K) int32
    const float* conv_w  = (const float*)d_in[2];
    const float* conv_b  = (const float*)d_in[3];
    const float* rconv_w = (const float*)d_in[4];
    const float* rconv_b = (const float*)d_in[5];
    float*       out     = (float*)d_out;

    const int B = 2;
    const int E = in_sizes[1] / (B * KNB);   // 8,000,000 / 20 = 400,000

    float* xT = (float*)d_ws;                // (B,E,C) = 51.2 MB scratch

    dim3 blk(256, 1, 1);
    dim3 grd((E + 255) / 256, B, 1);
    transpose_kernel<<<grd, blk, 0, stream>>>(x, xT, E);
    atten_kernel<<<grd, blk, 0, stream>>>(xT, Gi, conv_w, conv_b,
                                          rconv_w, rconv_b, out, E);
}

// Round 4
// 254.626 us; speedup vs baseline: 1.3163x; 1.3163x over previous
//
#include <hip/hip_runtime.h>
#include <math.h>

#define NCH 16    // C
#define KNB 10    // K neighbors
#define NTOP 4    // TOPK

// Prep: x (B,C,E) -> xT (B,E,C) rows (one 64B line per edge) + per-edge
// similarity-gather scalar d[b][e] = sum_c x[b,c,e]*conv_w[C+c], computed with
// the EXACT numpy einsum f32 chain (ascending c, sequential accum, no FMA) so
// the downstream top-k ordering bit-matches the reference. 4 edges/thread,
// float4 in and out.
__global__ __launch_bounds__(256) void prep_kernel(
    const float* __restrict__ x, const float* __restrict__ conv_w,
    float* __restrict__ xT, float* __restrict__ d, int E)
{
    const int b = blockIdx.y;
    const int q = blockIdx.x * blockDim.x + threadIdx.x;  // edge-quad
    const int e0 = q * 4;
    if (e0 >= E) return;

    float wcg[NCH];
#pragma unroll
    for (int c = 0; c < NCH; ++c) wcg[c] = conv_w[NCH + c];

    const float* xb = x + (size_t)b * NCH * E;
    float4 v[NCH];                       // v[c] = 4 consecutive edges of channel c
#pragma unroll
    for (int c = 0; c < NCH; ++c)
        v[c] = *(const float4*)(xb + (size_t)c * E + e0);   // coalesced 1KB/wave

    // Transpose in registers -> 4 rows of 16 floats, write as 4x float4 each.
    float* rowb = xT + ((size_t)b * E + e0) * NCH;
#pragma unroll
    for (int i = 0; i < 4; ++i) {
        float4* dst = (float4*)(rowb + (size_t)i * NCH);
        dst[0] = make_float4(i==0?v[0].x:i==1?v[0].y:i==2?v[0].z:v[0].w,
                             i==0?v[1].x:i==1?v[1].y:i==2?v[1].z:v[1].w,
                             i==0?v[2].x:i==1?v[2].y:i==2?v[2].z:v[2].w,
                             i==0?v[3].x:i==1?v[3].y:i==2?v[3].z:v[3].w);
        dst[1] = make_float4(i==0?v[4].x:i==1?v[4].y:i==2?v[4].z:v[4].w,
                             i==0?v[5].x:i==1?v[5].y:i==2?v[5].z:v[5].w,
                             i==0?v[6].x:i==1?v[6].y:i==2?v[6].z:v[6].w,
                             i==0?v[7].x:i==1?v[7].y:i==2?v[7].z:v[7].w);
        dst[2] = make_float4(i==0?v[8].x:i==1?v[8].y:i==2?v[8].z:v[8].w,
                             i==0?v[9].x:i==1?v[9].y:i==2?v[9].z:v[9].w,
                             i==0?v[10].x:i==1?v[10].y:i==2?v[10].z:v[10].w,
                             i==0?v[11].x:i==1?v[11].y:i==2?v[11].z:v[11].w);
        dst[3] = make_float4(i==0?v[12].x:i==1?v[12].y:i==2?v[12].z:v[12].w,
                             i==0?v[13].x:i==1?v[13].y:i==2?v[13].z:v[13].w,
                             i==0?v[14].x:i==1?v[14].y:i==2?v[14].z:v[14].w,
                             i==0?v[15].x:i==1?v[15].y:i==2?v[15].z:v[15].w);
    }

    // d for 4 edges: np-exact f32 sequential sums (no FMA), ascending c.
    float d0, d1, d2, d3;
    {
#pragma clang fp contract(off)
        float s0 = 0.0f, s1 = 0.0f, s2 = 0.0f, s3 = 0.0f;
#pragma unroll
        for (int c = 0; c < NCH; ++c) {
            s0 = s0 + v[c].x * wcg[c];
            s1 = s1 + v[c].y * wcg[c];
            s2 = s2 + v[c].z * wcg[c];
            s3 = s3 + v[c].w * wcg[c];
        }
        d0 = s0; d1 = s1; d2 = s2; d3 = s3;
    }
    *(float4*)(d + (size_t)b * E + e0) = make_float4(d0, d1, d2, d3);
}

// Atten: pass 1 gathers only the 4B d scalars (3.2MB table -> L2-resident),
// computes the np-exact f32 sigmoid chain (proven bit-matching in round 3),
// stable top-4, then gathers ONLY the 4 winners' 64B rows.
__global__ __launch_bounds__(256) void atten_kernel(
    const float* __restrict__ xT,      // (B,E,C)
    const float* __restrict__ d,       // (B,E)
    const int*   __restrict__ Gi,      // (B,E,K)
    const float* __restrict__ conv_w,  // (32,)
    const float* __restrict__ conv_b,  // (1,)
    const float* __restrict__ rconv_w, // (32,)
    const float* __restrict__ rconv_b, // (1,)
    float*       __restrict__ out,     // (B,C,E)
    int E)
{
    const int b = blockIdx.y;
    const int e = blockIdx.x * blockDim.x + threadIdx.x;
    if (e >= E) return;

    float wcx[NCH], wrx[NCH], wrg[NCH];
#pragma unroll
    for (int c = 0; c < NCH; ++c) {
        wcx[c] = conv_w[c];
        wrx[c] = rconv_w[c];
        wrg[c] = rconv_w[NCH + c];
    }
    const float  cb32 = conv_b[0];
    const double rb   = (double)rconv_b[0];

    // Own feature row (64B contiguous).
    const float4* xrow = (const float4*)(xT + ((size_t)b * E + e) * NCH);
    float xe[NCH];
#pragma unroll
    for (int i = 0; i < 4; ++i) {
        float4 t = xrow[i];
        xe[4*i+0] = t.x; xe[4*i+1] = t.y; xe[4*i+2] = t.z; xe[4*i+3] = t.w;
    }

    // eX for sim: np-exact f32 sequential sum, no FMA.
    float sX_c;
    {
#pragma clang fp contract(off)
        float s = 0.0f;
#pragma unroll
        for (int c = 0; c < NCH; ++c) s = s + xe[c] * wcx[c];
        sX_c = s;
    }
    // rw own-dot in f64 (accuracy only; bf16-rounded compare forgives).
    double xs_r = rb;
#pragma unroll
    for (int c = 0; c < NCH; ++c) xs_r += (double)xe[c] * (double)wrx[c];

    // Neighbor indices: 5x int2 (rows are 40B, 8B-aligned).
    const int2* gi2 = (const int2*)(Gi + ((size_t)b * E + e) * KNB);
    int j[KNB];
#pragma unroll
    for (int k = 0; k < 5; ++k) {
        int2 t = gi2[k];
        j[2*k+0] = t.x; j[2*k+1] = t.y;
    }

    // Pass 1: gather 4B d scalars, form np-exact f32 sims.
    const float* db = d + (size_t)b * E;
    float dk[KNB];
#pragma unroll
    for (int k = 0; k < KNB; ++k) dk[k] = db[j[k]];

    float sim[KNB];
#pragma unroll
    for (int k = 0; k < KNB; ++k) {
        float l = (dk[k] + sX_c) + cb32;       // left-assoc adds, as numpy
        float t = (float)exp(-(double)l);      // correctly-rounded f32 exp
        sim[k] = 1.0f / (1.0f + t);            // IEEE f32
    }

    // Pass 2: stable top-4 (strict > keeps lowest index on exact f32 ties),
    // gather winner rows (the only 64B random traffic), accumulate.
    float acc[NCH];
#pragma unroll
    for (int c = 0; c < NCH; ++c) acc[c] = 0.f;

    unsigned used = 0;
#pragma unroll
    for (int t = 0; t < NTOP; ++t) {
        float best = -INFINITY; int bi = 0; int bj = 0;
#pragma unroll
        for (int k = 0; k < KNB; ++k) {
            const bool ok = !(used & (1u << k)) && (sim[k] > best);
            best = ok ? sim[k] : best;
            bi   = ok ? k      : bi;
            bj   = ok ? j[k]   : bj;
        }
        used |= 1u << bi;

        const float4* grow = (const float4*)(xT + ((size_t)b * E + bj) * NCH);
        float g[NCH];
#pragma unroll
        for (int i = 0; i < 4; ++i) {
            float4 gv = grow[i];
            g[4*i+0] = gv.x; g[4*i+1] = gv.y; g[4*i+2] = gv.z; g[4*i+3] = gv.w;
        }
        double r = xs_r;
#pragma unroll
        for (int c = 0; c < NCH; ++c) r += (double)g[c] * (double)wrg[c];
        const float rw = (float)(1.0 / (1.0 + exp(-r)));
#pragma unroll
        for (int c = 0; c < NCH; ++c) acc[c] += g[c] * rw;
    }

    // out (B,C,E): 16 coalesced store streams.
    float* ob = out + (size_t)b * NCH * E;
#pragma unroll
    for (int c = 0; c < NCH; ++c) ob[(size_t)c * E + e] = xe[c] + acc[c];
}

extern "C" void kernel_launch(void* const* d_in, const int* in_sizes, int n_in,
                              void* d_out, int out_size, void* d_ws, size_t ws_size,
                              hipStream_t stream) {
    const float* x       = (const float*)d_in[0];  // (B,C,E,1) fp32
    const int*   Gi      = (const int*)  d_in[1];  // (B,E,K) int32
    const float* conv_w  = (const float*)d_in[2];
    const float* conv_b  = (const float*)d_in[3];
    const float* rconv_w = (const float*)d_in[4];
    const float* rconv_b = (const float*)d_in[5];
    float*       out     = (float*)d_out;

    const int B = 2;
    const int E = in_sizes[1] / (B * KNB);   // 400,000

    float* xT = (float*)d_ws;                          // (B,E,C) 51.2 MB
    float* dt = (float*)d_ws + (size_t)B * E * NCH;    // (B,E)    3.2 MB

    dim3 blk(256, 1, 1);
    dim3 grd_p(((E / 4) + 255) / 256, B, 1);
    prep_kernel<<<grd_p, blk, 0, stream>>>(x, conv_w, xT, dt, E);

    dim3 grd_a((E + 255) / 256, B, 1);
    atten_kernel<<<grd_a, blk, 0, stream>>>(xT, dt, Gi, conv_w, conv_b,
                                            rconv_w, rconv_b, out, E);
}

// Round 6
// 215.165 us; speedup vs baseline: 1.5578x; 1.1834x over previous
//
#include <hip/hip_runtime.h>
#include <math.h>

#define NCH  16    // C
#define KNB  10    // K neighbors
#define NTOP 4     // TOPK
#define TILE 512   // edges per prep block
#define PADE 514   // padded LDS row stride (floats): even (b64-aligned writes),
                   // 514%32=2 -> ~2-way read / 4-way write bank aliasing only

__device__ __forceinline__ unsigned short f32_to_bf16_rne(float f) {
    unsigned u = __float_as_uint(f);
    u += 0x7FFFu + ((u >> 16) & 1u);          // round-to-nearest-even
    return (unsigned short)(u >> 16);
}
__device__ __forceinline__ float bf16_to_f32(unsigned us) {
    return __uint_as_float(us << 16);
}

// Prep: stage x tile (16 ch x 512 edges, f32) in LDS, then
//  (a) d[b][e] = np-exact f32 sequential sum_c x*conv_w[C+c] (no FMA) — the
//      bit-exact similarity-gather scalar the top-k selection depends on,
//  (b) xT rows packed to bf16 (32B/row) with fully coalesced 16B/lane stores.
__global__ __launch_bounds__(256) void prep_kernel(
    const float* __restrict__ x, const float* __restrict__ conv_w,
    unsigned short* __restrict__ xTb, float* __restrict__ d, int E)
{
    __shared__ float lds[NCH * PADE];
    const int b  = blockIdx.y;
    const int e0 = blockIdx.x * TILE;
    const int t  = threadIdx.x;
    const int rem = min(TILE, E - e0);

    float wcg[NCH];
#pragma unroll
    for (int c = 0; c < NCH; ++c) wcg[c] = conv_w[NCH + c];

    // Load phase: float2 per channel per thread, coalesced 2KB rows.
    const float* xb = x + (size_t)b * NCH * E + e0;
    if (2 * t + 1 < rem) {                    // rem is always even
#pragma unroll
        for (int c = 0; c < NCH; ++c) {
            float2 v = *(const float2*)(xb + (size_t)c * E + 2 * t);
            lds[c * PADE + 2 * t]     = v.x;  // merges to ds_write_b64
            lds[c * PADE + 2 * t + 1] = v.y;
        }
    }
    __syncthreads();

    // d phase: rows t and t+256; conflict-free stride-1 LDS reads.
#pragma unroll
    for (int rr = 0; rr < 2; ++rr) {
        const int row = t + rr * 256;
        if (row < rem) {
#pragma clang fp contract(off)
            float s = 0.0f;
#pragma unroll
            for (int c = 0; c < NCH; ++c) s = s + lds[c * PADE + row] * wcg[c];
            d[(size_t)b * E + e0 + row] = s;  // coalesced 1KB store
        }
    }

    // Pack phase: 16B chunk f = t + r*256 covers row f/2, channels 8*(f&1)..+7.
    // Lane-contiguous 16B stores -> every store instr is 4KB fully coalesced.
    unsigned short* outb = xTb + ((size_t)b * E + e0) * NCH;
#pragma unroll
    for (int r = 0; r < 4; ++r) {
        const int f = t + r * 256;
        const int row = f >> 1, h = f & 1;
        if (row < rem) {
            float v[8];
#pragma unroll
            for (int k = 0; k < 8; ++k) v[k] = lds[(h * 8 + k) * PADE + row];
            uint4 pk;
            pk.x = (unsigned)f32_to_bf16_rne(v[0]) | ((unsigned)f32_to_bf16_rne(v[1]) << 16);
            pk.y = (unsigned)f32_to_bf16_rne(v[2]) | ((unsigned)f32_to_bf16_rne(v[3]) << 16);
            pk.z = (unsigned)f32_to_bf16_rne(v[4]) | ((unsigned)f32_to_bf16_rne(v[5]) << 16);
            pk.w = (unsigned)f32_to_bf16_rne(v[6]) | ((unsigned)f32_to_bf16_rne(v[7]) << 16);
            *(uint4*)(outb + (size_t)f * 8) = pk;
        }
    }
}

// Atten: d-gathers (L2-resident 3.2MB table) -> np-exact f32 sigmoid chain
// (proven bit-matching) -> stable top-4 -> THEN all 8 winner-row loads issued
// back-to-back (one latency) from the bf16 xT (25.6MB, L3-resident).
__global__ __launch_bounds__(256) void atten_kernel(
    const float*          __restrict__ x,       // (B,C,E) exact f32
    const unsigned short* __restrict__ xTb,     // (B,E,C) bf16
    const float*          __restrict__ d,       // (B,E)
    const int*            __restrict__ Gi,      // (B,E,K)
    const float* __restrict__ conv_w,  const float* __restrict__ conv_b,
    const float* __restrict__ rconv_w, const float* __restrict__ rconv_b,
    float* __restrict__ out, int E)
{
    const int b = blockIdx.y;
    const int e = blockIdx.x * blockDim.x + threadIdx.x;
    if (e >= E) return;

    float wcx[NCH], wrx[NCH], wrg[NCH];
#pragma unroll
    for (int c = 0; c < NCH; ++c) {
        wcx[c] = conv_w[c];
        wrx[c] = rconv_w[c];
        wrg[c] = rconv_w[NCH + c];
    }
    const float cb32 = conv_b[0];
    const float rb32 = rconv_b[0];

    // Own features from original x: exact f32, coalesced per channel.
    const float* xb = x + (size_t)b * NCH * E;
    float xe[NCH];
#pragma unroll
    for (int c = 0; c < NCH; ++c) xe[c] = xb[(size_t)c * E + e];

    // np-exact f32 sequential sum (no FMA) — selection-critical.
    float sX_c;
    {
#pragma clang fp contract(off)
        float s = 0.0f;
#pragma unroll
        for (int c = 0; c < NCH; ++c) s = s + xe[c] * wcx[c];
        sX_c = s;
    }
    // rw own-dot: output-accuracy only -> fast f32 FMA.
    float xs_r = rb32;
#pragma unroll
    for (int c = 0; c < NCH; ++c) xs_r = fmaf(xe[c], wrx[c], xs_r);

    // Neighbor indices (5x int2; rows 40B, 8B-aligned).
    const int2* gi2 = (const int2*)(Gi + ((size_t)b * E + e) * KNB);
    int j[KNB];
#pragma unroll
    for (int k = 0; k < 5; ++k) {
        int2 t2 = gi2[k];
        j[2 * k + 0] = t2.x; j[2 * k + 1] = t2.y;
    }

    // 10 independent 4B d-gathers (mostly L2 hits).
    const float* db = d + (size_t)b * E;
    float dk[KNB];
#pragma unroll
    for (int k = 0; k < KNB; ++k) dk[k] = db[j[k]];

    // np-exact sims: left-assoc f32 adds, correctly-rounded f32 exp, IEEE div.
    float sim[KNB];
#pragma unroll
    for (int k = 0; k < KNB; ++k) {
        float l = (dk[k] + sX_c) + cb32;
        float t = (float)exp(-(double)l);
        sim[k] = 1.0f / (1.0f + t);
    }

    // Stable top-4 (strict > keeps lowest index on exact f32 ties) — select
    // ALL winners first so the row loads can issue together.
    int bjv[NTOP];
    unsigned used = 0;
#pragma unroll
    for (int t = 0; t < NTOP; ++t) {
        float best = -INFINITY; int bi = 0; int bj = 0;
#pragma unroll
        for (int k = 0; k < KNB; ++k) {
            const bool ok = !(used & (1u << k)) && (sim[k] > best);
            best = ok ? sim[k] : best;
            bi   = ok ? k      : bi;
            bj   = ok ? j[k]   : bj;
        }
        used |= 1u << bi;
        bjv[t] = bj;
    }

    // 8 independent 16B gathers (4 winner rows x 32B bf16).
    uint4 ga[NTOP], gb[NTOP];
#pragma unroll
    for (int t = 0; t < NTOP; ++t) {
        const uint4* p = (const uint4*)(xTb + ((size_t)b * E + bjv[t]) * NCH);
        ga[t] = p[0]; gb[t] = p[1];
    }

    float acc[NCH];
#pragma unroll
    for (int c = 0; c < NCH; ++c) acc[c] = 0.f;

#pragma unroll
    for (int t = 0; t < NTOP; ++t) {
        float g[NCH];
        g[0]  = bf16_to_f32(ga[t].x & 0xFFFFu); g[1]  = bf16_to_f32(ga[t].x >> 16);
        g[2]  = bf16_to_f32(ga[t].y & 0xFFFFu); g[3]  = bf16_to_f32(ga[t].y >> 16);
        g[4]  = bf16_to_f32(ga[t].z & 0xFFFFu); g[5]  = bf16_to_f32(ga[t].z >> 16);
        g[6]  = bf16_to_f32(ga[t].w & 0xFFFFu); g[7]  = bf16_to_f32(ga[t].w >> 16);
        g[8]  = bf16_to_f32(gb[t].x & 0xFFFFu); g[9]  = bf16_to_f32(gb[t].x >> 16);
        g[10] = bf16_to_f32(gb[t].y & 0xFFFFu); g[11] = bf16_to_f32(gb[t].y >> 16);
        g[12] = bf16_to_f32(gb[t].z & 0xFFFFu); g[13] = bf16_to_f32(gb[t].z >> 16);
        g[14] = bf16_to_f32(gb[t].w & 0xFFFFu); g[15] = bf16_to_f32(gb[t].w >> 16);
        float r = xs_r;
#pragma unroll
        for (int c = 0; c < NCH; ++c) r = fmaf(g[c], wrg[c], r);
        const float rw = 1.0f / (1.0f + __expf(-r));
#pragma unroll
        for (int c = 0; c < NCH; ++c) acc[c] = fmaf(g[c], rw, acc[c]);
    }

    float* ob = out + (size_t)b * NCH * E;
#pragma unroll
    for (int c = 0; c < NCH; ++c) ob[(size_t)c * E + e] = xe[c] + acc[c];
}

extern "C" void kernel_launch(void* const* d_in, const int* in_sizes, int n_in,
                              void* d_out, int out_size, void* d_ws, size_t ws_size,
                              hipStream_t stream) {
    const float* x       = (const float*)d_in[0];  // (B,C,E,1) fp32
    const int*   Gi      = (const int*)  d_in[1];  // (B,E,K) int32
    const float* conv_w  = (const float*)d_in[2];
    const float* conv_b  = (const float*)d_in[3];
    const float* rconv_w = (const float*)d_in[4];
    const float* rconv_b = (const float*)d_in[5];
    float*       out     = (float*)d_out;

    const int B = 2;
    const int E = in_sizes[1] / (B * KNB);   // 400,000

    unsigned short* xTb = (unsigned short*)d_ws;                    // 25.6 MB
    float* dt = (float*)((char*)d_ws + (size_t)B * E * NCH * 2);    //  3.2 MB

    dim3 blk(256, 1, 1);
    dim3 grd_p((E + TILE - 1) / TILE, B, 1);
    prep_kernel<<<grd_p, blk, 0, stream>>>(x, conv_w, xTb, dt, E);

    dim3 grd_a((E + 255) / 256, B, 1);
    atten_kernel<<<grd_a, blk, 0, stream>>>(x, xTb, dt, Gi, conv_w, conv_b,
                                            rconv_w, rconv_b, out, E);
}